// Round 7
// baseline (430.064 us; speedup 1.0000x reference)
//
#include <hip/hip_runtime.h>
#include <hip/hip_bf16.h>
#include <hip/hip_cooperative_groups.h>

// NNConv R7: single cooperative persistent kernel for zero+deg+scan+cursor+
// edge-MFMA-compute (grid.sync between phases) + one gather_finalize launch.
// R6 post-mortem: 7 sequential launches cost ~95us of dispatch gaps; kernels
// themselves sum to ~135us. Fusion removes 5 gaps and amortizes weight
// staging across tiles. Non-cooperative fallback = R6 sequence (chosen by
// host-side queries only, so graph capture never sees a failed launch).
// N=50000, E=800000, IN=16, OUT=16, HID=32.

namespace cg = cooperative_groups;

#define N_NODES 50000
#define N_EDGES 800000
#define IN_D    16
#define OUT_D   16
#define HID_D   32
#define NBLK_E  (N_EDGES / 256)          // 3125, exact
#define NBLK_N  ((N_NODES + 255) / 256)  // 196
#define KTILES  17                        // 16 tiles of h*x + 1 tile for b2

typedef __attribute__((ext_vector_type(8))) short bfrag8;
typedef __attribute__((ext_vector_type(4))) float f32x4;

__device__ __forceinline__ void fma4(float a, const float4 w, float4& m) {
    m.x = fmaf(a, w.x, m.x);
    m.y = fmaf(a, w.y, m.y);
    m.z = fmaf(a, w.z, m.z);
    m.w = fmaf(a, w.w, m.w);
}
__device__ __forceinline__ float4 add4(float4 a, float4 b) {
    return make_float4(a.x + b.x, a.y + b.y, a.z + b.z, a.w + b.w);
}
__device__ __forceinline__ int clampn(int v) {
    return v < 0 ? 0 : (v >= N_NODES ? N_NODES - 1 : v);
}
__device__ __forceinline__ bfrag8 pack8(const float* p) {
    union { bfrag8 v; __hip_bfloat162 h[4]; } u;
    u.h[0] = __float22bfloat162_rn(make_float2(p[0], p[1]));
    u.h[1] = __float22bfloat162_rn(make_float2(p[2], p[3]));
    u.h[2] = __float22bfloat162_rn(make_float2(p[4], p[5]));
    u.h[3] = __float22bfloat162_rn(make_float2(p[6], p[7]));
    return u.v;
}

// ---------------- shared device helpers for edge compute ----------------

__device__ __forceinline__ void stage_weights(
    const float* __restrict__ w1, const float* __restrict__ b1,
    const float* __restrict__ w2, const float* __restrict__ b2,
    float4* s_w1, float4* s_b1, bfrag8* s_B, int t)
{
    const float4* w1v = reinterpret_cast<const float4*>(w1);
    const float4* b1v = reinterpret_cast<const float4*>(b1);
    if (t < IN_D * HID_D / 4) s_w1[t] = w1v[t];
    if (t < HID_D / 4)        s_b1[t] = b1v[t];

    __hip_bfloat16* bp = reinterpret_cast<__hip_bfloat16*>(s_B);
    for (int r = t; r < KTILES * 32; r += 256) {
        const int tile = r >> 5, q = (r >> 3) & 3, j = r & 7;
        const int base = ((tile * 4 + q) * 16) * 8 + j;
        float vals[16];
        if (r < 512) {
            const float4* wr = reinterpret_cast<const float4*>(w2) + r * 4;
            float4 v0 = wr[0], v1 = wr[1], v2 = wr[2], v3 = wr[3];
            vals[0]=v0.x; vals[1]=v0.y; vals[2]=v0.z; vals[3]=v0.w;
            vals[4]=v1.x; vals[5]=v1.y; vals[6]=v1.z; vals[7]=v1.w;
            vals[8]=v2.x; vals[9]=v2.y; vals[10]=v2.z; vals[11]=v2.w;
            vals[12]=v3.x; vals[13]=v3.y; vals[14]=v3.z; vals[15]=v3.w;
        } else if (r < 528) {
            const float4* br = reinterpret_cast<const float4*>(b2) + (r - 512) * 4;
            float4 v0 = br[0], v1 = br[1], v2 = br[2], v3 = br[3];
            vals[0]=v0.x; vals[1]=v0.y; vals[2]=v0.z; vals[3]=v0.w;
            vals[4]=v1.x; vals[5]=v1.y; vals[6]=v1.z; vals[7]=v1.w;
            vals[8]=v2.x; vals[9]=v2.y; vals[10]=v2.z; vals[11]=v2.w;
            vals[12]=v3.x; vals[13]=v3.y; vals[14]=v3.z; vals[15]=v3.w;
        } else {
            #pragma unroll
            for (int o = 0; o < 16; ++o) vals[o] = 0.f;
        }
        #pragma unroll
        for (int o = 0; o < 16; ++o) bp[base + o * 8] = __float2bfloat16(vals[o]);
    }
}

__device__ __forceinline__ void edge_mlp_to_lds(
    const float* __restrict__ ea, int e,
    const float4* s_w1, const float4* s_b1, float* s_hm, int t)
{
    float eav[IN_D];
    {
        const float4* eap = reinterpret_cast<const float4*>(ea) + (size_t)e * 4;
        float4 a0 = eap[0], a1 = eap[1], a2 = eap[2], a3 = eap[3];
        eav[0]=a0.x;  eav[1]=a0.y;  eav[2]=a0.z;  eav[3]=a0.w;
        eav[4]=a1.x;  eav[5]=a1.y;  eav[6]=a1.z;  eav[7]=a1.w;
        eav[8]=a2.x;  eav[9]=a2.y;  eav[10]=a2.z; eav[11]=a2.w;
        eav[12]=a3.x; eav[13]=a3.y; eav[14]=a3.z; eav[15]=a3.w;
    }
    float4 hv[HID_D / 4];
    #pragma unroll
    for (int j = 0; j < HID_D / 4; ++j) hv[j] = s_b1[j];
    #pragma unroll
    for (int i = 0; i < IN_D; ++i) {
        const float xi = eav[i];
        #pragma unroll
        for (int j = 0; j < HID_D / 4; ++j) fma4(xi, s_w1[i * (HID_D / 4) + j], hv[j]);
    }
    __hip_bfloat16* s_h = reinterpret_cast<__hip_bfloat16*>(s_hm);
    #pragma unroll
    for (int j = 0; j < HID_D / 4; ++j) {
        s_h[(4*j+0)*256 + t] = __float2bfloat16(fmaxf(hv[j].x, 0.f));
        s_h[(4*j+1)*256 + t] = __float2bfloat16(fmaxf(hv[j].y, 0.f));
        s_h[(4*j+2)*256 + t] = __float2bfloat16(fmaxf(hv[j].z, 0.f));
        s_h[(4*j+3)*256 + t] = __float2bfloat16(fmaxf(hv[j].w, 0.f));
    }
}

__device__ __forceinline__ void mfma_msgs(
    const float* __restrict__ x, const int* s_src,
    const float* s_hm_in, const bfrag8* s_B, int t, f32x4* accs)
{
    const __hip_bfloat16* s_h = reinterpret_cast<const __hip_bfloat16*>(s_hm_in);
    const int wbase = t & 192;
    const int q     = (t >> 4) & 3;
    const int n     = t & 15;
    const int qh    = q >> 1;
    const int i0    = (q & 1) * 8;

    #pragma unroll
    for (int sub = 0; sub < 4; ++sub) {
        const int posB = wbase + sub * 16 + n;
        const int srcB = s_src[posB];
        float xr[8];
        {
            const float4* xp = reinterpret_cast<const float4*>(x) + (size_t)srcB * 4 + (i0 >> 2);
            float4 xa = xp[0], xb = xp[1];
            xr[0]=xa.x; xr[1]=xa.y; xr[2]=xa.z; xr[3]=xa.w;
            xr[4]=xb.x; xr[5]=xb.y; xr[6]=xb.z; xr[7]=xb.w;
        }
        f32x4 acc = {0.f, 0.f, 0.f, 0.f};
        #pragma unroll
        for (int tile = 0; tile < 16; ++tile) {
            const int k = 2 * tile + qh;
            const float hval = __bfloat162float(s_h[k * 256 + posB]);
            float p[8];
            #pragma unroll
            for (int j = 0; j < 8; ++j) p[j] = hval * xr[j];
            bfrag8 av = pack8(p);
            bfrag8 bv = s_B[tile * 64 + (t & 63)];
            acc = __builtin_amdgcn_mfma_f32_16x16x32_bf16(av, bv, acc, 0, 0, 0);
        }
        {
            bfrag8 a16;
            if (qh == 0) a16 = pack8(xr);
            else { bfrag8 z = {0,0,0,0,0,0,0,0}; a16 = z; }
            bfrag8 bv = s_B[16 * 64 + (t & 63)];
            acc = __builtin_amdgcn_mfma_f32_16x16x32_bf16(a16, bv, acc, 0, 0, 0);
        }
        accs[sub] = acc;
    }
}

__device__ __forceinline__ void write_cfrags(float* s_hm, const f32x4* accs, int t) {
    const int wbase = t & 192;
    const int q     = (t >> 4) & 3;
    const int n     = t & 15;
    #pragma unroll
    for (int sub = 0; sub < 4; ++sub) {
        #pragma unroll
        for (int r = 0; r < 4; ++r) {
            const int er = wbase + sub * 16 + q * 4 + r;
            s_hm[er * 17 + n] = accs[sub][r];
        }
    }
}

// ---------------- MEGA cooperative kernel: phases 1-4 ----------------

__global__ __launch_bounds__(256) void mega_k(
    const float* __restrict__ x,
    const int*   __restrict__ ei,
    const float* __restrict__ ea,
    const float* __restrict__ w1,
    const float* __restrict__ b1,
    const float* __restrict__ w2,
    const float* __restrict__ b2,
    int*   __restrict__ deg,
    int*   __restrict__ loc,
    int*   __restrict__ bsum,
    int*   __restrict__ bofs,
    int*   __restrict__ cursor,
    float* __restrict__ msg)
{
    cg::grid_group grid = cg::this_grid();

    __shared__ bfrag8 s_B[KTILES * 64];        // 17408 B
    __shared__ float  s_hm[256 * 17];          // 17408 B (aliased as scan buf)
    __shared__ float4 s_w1[IN_D * HID_D / 4];  // 2 KB
    __shared__ float4 s_b1[HID_D / 4];         // 128 B
    __shared__ int    s_src[256];              // 1 KB   -> total ~38.0 KB

    const int t   = threadIdx.x;
    const int nb  = gridDim.x;
    const int nth = nb * 256;
    const int gt  = blockIdx.x * 256 + t;
    int* s_scan = reinterpret_cast<int*>(s_hm);

    // weights staged once per block; visibility via the grid.syncs below
    stage_weights(w1, b1, w2, b2, s_w1, s_b1, s_B, t);

    // phase 1: zero deg
    for (int i = gt; i < N_NODES; i += nth) deg[i] = 0;
    grid.sync();

    // phase 2: degree count
    for (int e = gt; e < N_EDGES; e += nth)
        atomicAdd(&deg[clampn(ei[N_EDGES + e])], 1);
    grid.sync();

    // phase 3a: per-256-block local exclusive scan
    for (int blk = blockIdx.x; blk < NBLK_N; blk += nb) {
        const int i = blk * 256 + t;
        const int v = (i < N_NODES) ? deg[i] : 0;
        __syncthreads();
        s_scan[t] = v;
        __syncthreads();
        #pragma unroll
        for (int d = 1; d < 256; d <<= 1) {
            int tmp = (t >= d) ? s_scan[t - d] : 0;
            __syncthreads();
            s_scan[t] += tmp;
            __syncthreads();
        }
        loc[i] = s_scan[t] - v;
        if (t == 255) bsum[blk] = s_scan[255];
    }
    grid.sync();

    // phase 3b: scan of block sums (block 0 only)
    if (blockIdx.x == 0) {
        const int v = (t < NBLK_N) ? bsum[t] : 0;
        s_scan[t] = v;
        __syncthreads();
        #pragma unroll
        for (int d = 1; d < 256; d <<= 1) {
            int tmp = (t >= d) ? s_scan[t - d] : 0;
            __syncthreads();
            s_scan[t] += tmp;
            __syncthreads();
        }
        bofs[t] = s_scan[t] - v;
    }
    grid.sync();

    // phase 3c: cursor = global exclusive prefix
    for (int i = gt; i < N_NODES; i += nth) cursor[i] = loc[i] + bofs[i >> 8];
    grid.sync();

    // phase 4: edge compute, persistent loop over 256-edge tiles
    for (int tile = blockIdx.x; tile < NBLK_E; tile += nb) {
        __syncthreads();   // protect s_hm/s_src reuse from previous iteration
        const int e   = tile * 256 + t;
        const int src = clampn(ei[e]);
        const int dst = clampn(ei[N_EDGES + e]);
        const int slot = atomicAdd(&cursor[dst], 1);
        s_src[t] = src;

        edge_mlp_to_lds(ea, e, s_w1, s_b1, s_hm, t);
        __syncthreads();   // h + s_src visible

        f32x4 accs[4];
        mfma_msgs(x, s_src, s_hm, s_B, t, accs);
        __syncthreads();   // all s_h reads done
        write_cfrags(s_hm, accs, t);
        __syncthreads();   // msg rows visible

        const float* p = &s_hm[t * 17];
        float4* mp = reinterpret_cast<float4*>(msg + (size_t)slot * 16);
        mp[0] = make_float4(p[0],  p[1],  p[2],  p[3]);
        mp[1] = make_float4(p[4],  p[5],  p[6],  p[7]);
        mp[2] = make_float4(p[8],  p[9],  p[10], p[11]);
        mp[3] = make_float4(p[12], p[13], p[14], p[15]);
    }
}

// ---------------- fallback scaffolding (non-cooperative path) ----------------

__global__ __launch_bounds__(256) void zero_k(int* __restrict__ p, int n) {
    const int i = blockIdx.x * 256 + threadIdx.x;
    if (i < n) p[i] = 0;
}

__global__ __launch_bounds__(256) void deg_k(const int* __restrict__ ei,
                                             int* __restrict__ deg) {
    const int e = blockIdx.x * 256 + threadIdx.x;
    atomicAdd(&deg[clampn(ei[N_EDGES + e])], 1);
}

__global__ __launch_bounds__(256) void scan_a(const int* __restrict__ deg,
                                              int* __restrict__ loc,
                                              int* __restrict__ bsum) {
    __shared__ int s[256];
    const int t = threadIdx.x;
    const int i = blockIdx.x * 256 + t;
    const int v = (i < N_NODES) ? deg[i] : 0;
    s[t] = v;
    __syncthreads();
    #pragma unroll
    for (int d = 1; d < 256; d <<= 1) {
        int tmp = (t >= d) ? s[t - d] : 0;
        __syncthreads();
        s[t] += tmp;
        __syncthreads();
    }
    loc[i] = s[t] - v;
    if (t == 255) bsum[blockIdx.x] = s[255];
}

__global__ __launch_bounds__(256) void scan_b(const int* __restrict__ bsum,
                                              int* __restrict__ bofs) {
    __shared__ int s[256];
    const int t = threadIdx.x;
    const int v = (t < NBLK_N) ? bsum[t] : 0;
    s[t] = v;
    __syncthreads();
    #pragma unroll
    for (int d = 1; d < 256; d <<= 1) {
        int tmp = (t >= d) ? s[t - d] : 0;
        __syncthreads();
        s[t] += tmp;
        __syncthreads();
    }
    bofs[t] = s[t] - v;
}

__global__ __launch_bounds__(256) void init_cursor(const int* __restrict__ loc,
                                                   const int* __restrict__ bofs,
                                                   int* __restrict__ cursor) {
    const int i = blockIdx.x * 256 + threadIdx.x;
    if (i < N_NODES) cursor[i] = loc[i] + bofs[i >> 8];
}

__global__ __launch_bounds__(256) void edge_scatter(
    const float* __restrict__ x,
    const int*   __restrict__ ei,
    const float* __restrict__ ea,
    const float* __restrict__ w1,
    const float* __restrict__ b1,
    const float* __restrict__ w2,
    const float* __restrict__ b2,
    int*   __restrict__ cursor,
    float* __restrict__ msg)
{
    __shared__ bfrag8 s_B[KTILES * 64];
    __shared__ float  s_hm[256 * 17];
    __shared__ float4 s_w1[IN_D * HID_D / 4];
    __shared__ float4 s_b1[HID_D / 4];
    __shared__ int    s_src[256];

    const int t = threadIdx.x;
    const int e = blockIdx.x * 256 + t;

    const int src = clampn(ei[e]);
    const int dst = clampn(ei[N_EDGES + e]);
    const int slot = atomicAdd(&cursor[dst], 1);
    s_src[t] = src;

    stage_weights(w1, b1, w2, b2, s_w1, s_b1, s_B, t);
    __syncthreads();

    edge_mlp_to_lds(ea, e, s_w1, s_b1, s_hm, t);
    __syncthreads();

    f32x4 accs[4];
    mfma_msgs(x, s_src, s_hm, s_B, t, accs);
    __syncthreads();
    write_cfrags(s_hm, accs, t);
    __syncthreads();

    const float* p = &s_hm[t * 17];
    float4* mp = reinterpret_cast<float4*>(msg + (size_t)slot * 16);
    mp[0] = make_float4(p[0],  p[1],  p[2],  p[3]);
    mp[1] = make_float4(p[4],  p[5],  p[6],  p[7]);
    mp[2] = make_float4(p[8],  p[9],  p[10], p[11]);
    mp[3] = make_float4(p[12], p[13], p[14], p[15]);
}

// ---------------- gather + finalize (separate launch: full CU spread) ----------------

__global__ __launch_bounds__(256) void gather_finalize(
    const float* __restrict__ x,
    const float* __restrict__ root,
    const float* __restrict__ bias,
    const float* __restrict__ msg,
    const int*   __restrict__ cursor,   // post-edge: segment END
    const int*   __restrict__ deg,
    float* __restrict__ out)
{
    __shared__ float4 s_root[IN_D * OUT_D / 4];
    __shared__ float4 s_bias[OUT_D / 4];
    const int t = threadIdx.x;
    if (t < IN_D * OUT_D / 4) s_root[t] = reinterpret_cast<const float4*>(root)[t];
    if (t < OUT_D / 4)        s_bias[t] = reinterpret_cast<const float4*>(bias)[t];
    __syncthreads();

    const int n = blockIdx.x * 256 + t;
    if (n >= N_NODES) return;

    const int d   = deg[n];
    const int end = cursor[n];
    const int j0  = end - d;

    float4 a0 = make_float4(0.f,0.f,0.f,0.f), a1 = a0, a2 = a0, a3 = a0;
    for (int j = j0; j < end; ++j) {
        const float4* mp = reinterpret_cast<const float4*>(msg + (size_t)j * 16);
        a0 = add4(a0, mp[0]); a1 = add4(a1, mp[1]);
        a2 = add4(a2, mp[2]); a3 = add4(a3, mp[3]);
    }

    const float inv = 1.0f / (float)(d > 1 ? d : 1);
    float4 m0 = make_float4(a0.x*inv + s_bias[0].x, a0.y*inv + s_bias[0].y,
                            a0.z*inv + s_bias[0].z, a0.w*inv + s_bias[0].w);
    float4 m1 = make_float4(a1.x*inv + s_bias[1].x, a1.y*inv + s_bias[1].y,
                            a1.z*inv + s_bias[1].z, a1.w*inv + s_bias[1].w);
    float4 m2 = make_float4(a2.x*inv + s_bias[2].x, a2.y*inv + s_bias[2].y,
                            a2.z*inv + s_bias[2].z, a2.w*inv + s_bias[2].w);
    float4 m3 = make_float4(a3.x*inv + s_bias[3].x, a3.y*inv + s_bias[3].y,
                            a3.z*inv + s_bias[3].z, a3.w*inv + s_bias[3].w);

    float xs[IN_D];
    {
        const float4* xp = reinterpret_cast<const float4*>(x) + (size_t)n * 4;
        float4 b0 = xp[0], b1v = xp[1], b2v = xp[2], b3 = xp[3];
        xs[0]=b0.x;  xs[1]=b0.y;  xs[2]=b0.z;  xs[3]=b0.w;
        xs[4]=b1v.x; xs[5]=b1v.y; xs[6]=b1v.z; xs[7]=b1v.w;
        xs[8]=b2v.x; xs[9]=b2v.y; xs[10]=b2v.z; xs[11]=b2v.w;
        xs[12]=b3.x; xs[13]=b3.y; xs[14]=b3.z; xs[15]=b3.w;
    }
    #pragma unroll
    for (int i = 0; i < IN_D; ++i) {
        const float xi = xs[i];
        fma4(xi, s_root[i*4+0], m0);
        fma4(xi, s_root[i*4+1], m1);
        fma4(xi, s_root[i*4+2], m2);
        fma4(xi, s_root[i*4+3], m3);
    }

    float4* op = reinterpret_cast<float4*>(out) + (size_t)n * 4;
    op[0] = m0; op[1] = m1; op[2] = m2; op[3] = m3;
}

extern "C" void kernel_launch(void* const* d_in, const int* in_sizes, int n_in,
                              void* d_out, int out_size, void* d_ws, size_t ws_size,
                              hipStream_t stream) {
    const float* x    = (const float*)d_in[0];
    const int*   ei   = (const int*)  d_in[1];
    const float* ea   = (const float*)d_in[2];
    const float* w1   = (const float*)d_in[3];
    const float* b1   = (const float*)d_in[4];
    const float* w2   = (const float*)d_in[5];
    const float* b2   = (const float*)d_in[6];
    const float* root = (const float*)d_in[7];
    const float* bias = (const float*)d_in[8];
    float* out = (float*)d_out;

    // ws layout (~51.8 MB, proven in R6)
    int* deg    = (int*)d_ws;                 // 50000
    int* loc    = deg + N_NODES;              // 50176
    int* bsum   = loc + NBLK_N * 256;         // 256 (196 used)
    int* bofs   = bsum + 256;                 // 256
    int* cursor = bofs + 256;                 // 50000
    float* msg  = (float*)(cursor + N_NODES); // E*16 f32

    // decide cooperative path by queries only (never a failed launch in capture)
    bool coop = false;
    int grid = 0;
    {
        int dev = 0;
        hipDeviceProp_t props;
        if (hipGetDevice(&dev) == hipSuccess &&
            hipGetDeviceProperties(&props, dev) == hipSuccess &&
            props.cooperativeLaunch) {
            int nbpc = 0;
            if (hipOccupancyMaxActiveBlocksPerMultiprocessor(&nbpc, mega_k, 256, 0) == hipSuccess
                && nbpc > 0) {
                grid = nbpc * props.multiProcessorCount;
                if (grid > NBLK_E) grid = NBLK_E;
                coop = (grid > 0);
            }
        }
    }

    if (coop) {
        void* kargs[] = { (void*)&x, (void*)&ei, (void*)&ea, (void*)&w1, (void*)&b1,
                          (void*)&w2, (void*)&b2, (void*)&deg, (void*)&loc,
                          (void*)&bsum, (void*)&bofs, (void*)&cursor, (void*)&msg };
        hipLaunchCooperativeKernel((void*)mega_k, dim3(grid), dim3(256),
                                   kargs, 0, stream);
    } else {
        zero_k      <<<(N_NODES + 255) / 256, 256, 0, stream>>>(deg, N_NODES);
        deg_k       <<<NBLK_E, 256, 0, stream>>>(ei, deg);
        scan_a      <<<NBLK_N, 256, 0, stream>>>(deg, loc, bsum);
        scan_b      <<<1,      256, 0, stream>>>(bsum, bofs);
        init_cursor <<<NBLK_N, 256, 0, stream>>>(loc, bofs, cursor);
        edge_scatter<<<NBLK_E, 256, 0, stream>>>(x, ei, ea, w1, b1, w2, b2, cursor, msg);
    }
    gather_finalize<<<NBLK_N, 256, 0, stream>>>(x, root, bias, msg, cursor, deg, out);
}

// Round 8
// 236.719 us; speedup vs baseline: 1.8168x; 1.8168x over previous
//
#include <hip/hip_runtime.h>
#include <hip/hip_bf16.h>
#include <hip/hip_fp16.h>

// NNConv R8: revert R7's cooperative fusion (grid.sync barriers smeared VALU
// to 7.7% busy -> 2x regression). R6 discrete-launch structure with:
//  (a) 7 -> 5 graph nodes: memset(deg+gtot) / deg_k / scan_fused (block-local
//      scan + atomic global base; segment ORDER across blocks is irrelevant,
//      only per-node contiguity) / edge_scatter / gather_finalize.
//  (b) MFMA path switched bf16 -> fp16: A-frag build per K-tile drops from
//      8 v_mul_f32 + 4 cvt to 1 dup + 4 v_pk_mul_f16, and fp16's 10-bit
//      mantissa improves absmax (values well inside fp16 range; fp32 accum).
// N=50000, E=800000, IN=16, OUT=16, HID=32.

#define N_NODES 50000
#define N_EDGES 800000
#define IN_D    16
#define OUT_D   16
#define HID_D   32
#define NBLK_E  (N_EDGES / 256)          // 3125, exact
#define NBLK_N  ((N_NODES + 255) / 256)  // 196
#define KTILES  17                        // 16 tiles of h*x + 1 tile for b2

typedef __attribute__((ext_vector_type(8))) _Float16 hfrag8;
typedef __attribute__((ext_vector_type(4))) float f32x4;

__device__ __forceinline__ void fma4(float a, const float4 w, float4& m) {
    m.x = fmaf(a, w.x, m.x);
    m.y = fmaf(a, w.y, m.y);
    m.z = fmaf(a, w.z, m.z);
    m.w = fmaf(a, w.w, m.w);
}
__device__ __forceinline__ float4 add4(float4 a, float4 b) {
    return make_float4(a.x + b.x, a.y + b.y, a.z + b.z, a.w + b.w);
}
__device__ __forceinline__ int clampn(int v) {
    return v < 0 ? 0 : (v >= N_NODES ? N_NODES - 1 : v);
}

// ---------------- scaffolding ----------------

__global__ __launch_bounds__(256) void deg_k(const int* __restrict__ ei,
                                             int* __restrict__ deg) {
    const int e = blockIdx.x * 256 + threadIdx.x;
    atomicAdd(&deg[clampn(ei[N_EDGES + e])], 1);
}

// one-launch scan: block-local exclusive scan + atomic global base.
// cursor[n] = base(block) + local_excl(n). Bases are block-arrival-ordered,
// NOT node-ordered -- fine: gather only needs [end-deg, end) contiguous.
__global__ __launch_bounds__(256) void scan_fused(const int* __restrict__ deg,
                                                  int* __restrict__ cursor,
                                                  int* __restrict__ gtot) {
    __shared__ int s[256];
    __shared__ int sbase;
    const int t = threadIdx.x;
    const int i = blockIdx.x * 256 + t;
    const int v = (i < N_NODES) ? deg[i] : 0;
    s[t] = v;
    __syncthreads();
    #pragma unroll
    for (int d = 1; d < 256; d <<= 1) {
        int tmp = (t >= d) ? s[t - d] : 0;
        __syncthreads();
        s[t] += tmp;
        __syncthreads();
    }
    if (t == 255) sbase = atomicAdd(gtot, s[255]);
    __syncthreads();
    if (i < N_NODES) cursor[i] = sbase + s[t] - v;
}

// ---------------- edge compute (fp16 MFMA) ----------------

__device__ __forceinline__ void stage_weights(
    const float* __restrict__ w1, const float* __restrict__ b1,
    const float* __restrict__ w2, const float* __restrict__ b2,
    float4* s_w1, float4* s_b1, hfrag8* s_B, int t)
{
    const float4* w1v = reinterpret_cast<const float4*>(w1);
    const float4* b1v = reinterpret_cast<const float4*>(b1);
    if (t < IN_D * HID_D / 4) s_w1[t] = w1v[t];
    if (t < HID_D / 4)        s_b1[t] = b1v[t];

    __half* bp = reinterpret_cast<__half*>(s_B);
    for (int r = t; r < KTILES * 32; r += 256) {
        const int tile = r >> 5, q = (r >> 3) & 3, j = r & 7;
        const int base = ((tile * 4 + q) * 16) * 8 + j;
        float vals[16];
        if (r < 512) {
            const float4* wr = reinterpret_cast<const float4*>(w2) + r * 4;
            float4 v0 = wr[0], v1 = wr[1], v2 = wr[2], v3 = wr[3];
            vals[0]=v0.x; vals[1]=v0.y; vals[2]=v0.z; vals[3]=v0.w;
            vals[4]=v1.x; vals[5]=v1.y; vals[6]=v1.z; vals[7]=v1.w;
            vals[8]=v2.x; vals[9]=v2.y; vals[10]=v2.z; vals[11]=v2.w;
            vals[12]=v3.x; vals[13]=v3.y; vals[14]=v3.z; vals[15]=v3.w;
        } else if (r < 528) {
            const float4* br = reinterpret_cast<const float4*>(b2) + (r - 512) * 4;
            float4 v0 = br[0], v1 = br[1], v2 = br[2], v3 = br[3];
            vals[0]=v0.x; vals[1]=v0.y; vals[2]=v0.z; vals[3]=v0.w;
            vals[4]=v1.x; vals[5]=v1.y; vals[6]=v1.z; vals[7]=v1.w;
            vals[8]=v2.x; vals[9]=v2.y; vals[10]=v2.z; vals[11]=v2.w;
            vals[12]=v3.x; vals[13]=v3.y; vals[14]=v3.z; vals[15]=v3.w;
        } else {
            #pragma unroll
            for (int o = 0; o < 16; ++o) vals[o] = 0.f;
        }
        #pragma unroll
        for (int o = 0; o < 16; ++o) bp[base + o * 8] = __float2half(vals[o]);
    }
}

__device__ __forceinline__ void edge_mlp_to_lds(
    const float* __restrict__ ea, int e,
    const float4* s_w1, const float4* s_b1, float* s_hm, int t)
{
    float eav[IN_D];
    {
        const float4* eap = reinterpret_cast<const float4*>(ea) + (size_t)e * 4;
        float4 a0 = eap[0], a1 = eap[1], a2 = eap[2], a3 = eap[3];
        eav[0]=a0.x;  eav[1]=a0.y;  eav[2]=a0.z;  eav[3]=a0.w;
        eav[4]=a1.x;  eav[5]=a1.y;  eav[6]=a1.z;  eav[7]=a1.w;
        eav[8]=a2.x;  eav[9]=a2.y;  eav[10]=a2.z; eav[11]=a2.w;
        eav[12]=a3.x; eav[13]=a3.y; eav[14]=a3.z; eav[15]=a3.w;
    }
    float4 hv[HID_D / 4];
    #pragma unroll
    for (int j = 0; j < HID_D / 4; ++j) hv[j] = s_b1[j];
    #pragma unroll
    for (int i = 0; i < IN_D; ++i) {
        const float xi = eav[i];
        #pragma unroll
        for (int j = 0; j < HID_D / 4; ++j) fma4(xi, s_w1[i * (HID_D / 4) + j], hv[j]);
    }
    __half* s_h = reinterpret_cast<__half*>(s_hm);
    #pragma unroll
    for (int j = 0; j < HID_D / 4; ++j) {
        s_h[(4*j+0)*256 + t] = __float2half(fmaxf(hv[j].x, 0.f));
        s_h[(4*j+1)*256 + t] = __float2half(fmaxf(hv[j].y, 0.f));
        s_h[(4*j+2)*256 + t] = __float2half(fmaxf(hv[j].z, 0.f));
        s_h[(4*j+3)*256 + t] = __float2half(fmaxf(hv[j].w, 0.f));
    }
}

__device__ __forceinline__ void mfma_msgs(
    const float* __restrict__ x, const int* s_src,
    const float* s_hm_in, const hfrag8* s_B, int t, f32x4* accs)
{
    const __half* s_h = reinterpret_cast<const __half*>(s_hm_in);
    const int wbase = t & 192;
    const int q     = (t >> 4) & 3;
    const int n     = t & 15;
    const int qh    = q >> 1;
    const int i0    = (q & 1) * 8;

    #pragma unroll
    for (int sub = 0; sub < 4; ++sub) {
        const int posB = wbase + sub * 16 + n;
        const int srcB = s_src[posB];
        __half2 xh[4];                      // this quad's 8 x values, fp16 pairs
        {
            const float4* xp = reinterpret_cast<const float4*>(x) + (size_t)srcB * 4 + (i0 >> 2);
            float4 xa = xp[0], xb = xp[1];
            xh[0] = __float22half2_rn(make_float2(xa.x, xa.y));
            xh[1] = __float22half2_rn(make_float2(xa.z, xa.w));
            xh[2] = __float22half2_rn(make_float2(xb.x, xb.y));
            xh[3] = __float22half2_rn(make_float2(xb.z, xb.w));
        }
        f32x4 acc = {0.f, 0.f, 0.f, 0.f};
        #pragma unroll
        for (int tile = 0; tile < 16; ++tile) {
            const int k = 2 * tile + qh;
            const __half2 hh = __half2half2(s_h[k * 256 + posB]);
            union { hfrag8 v; __half2 h[4]; } a;
            a.h[0] = __hmul2(hh, xh[0]);
            a.h[1] = __hmul2(hh, xh[1]);
            a.h[2] = __hmul2(hh, xh[2]);
            a.h[3] = __hmul2(hh, xh[3]);
            acc = __builtin_amdgcn_mfma_f32_16x16x32_f16(a.v, s_B[tile * 64 + (t & 63)], acc, 0, 0, 0);
        }
        {   // b2 tile: rows 512..527 are x_i (pseudo h=1), 528..543 zero
            union { hfrag8 v; __half2 h[4]; } a;
            if (qh == 0) { a.h[0]=xh[0]; a.h[1]=xh[1]; a.h[2]=xh[2]; a.h[3]=xh[3]; }
            else { hfrag8 z = {0,0,0,0,0,0,0,0}; a.v = z; }
            acc = __builtin_amdgcn_mfma_f32_16x16x32_f16(a.v, s_B[16 * 64 + (t & 63)], acc, 0, 0, 0);
        }
        accs[sub] = acc;
    }
}

__device__ __forceinline__ void write_cfrags(float* s_hm, const f32x4* accs, int t) {
    const int wbase = t & 192;
    const int q     = (t >> 4) & 3;
    const int n     = t & 15;
    #pragma unroll
    for (int sub = 0; sub < 4; ++sub) {
        #pragma unroll
        for (int r = 0; r < 4; ++r) {
            const int er = wbase + sub * 16 + q * 4 + r;
            s_hm[er * 17 + n] = accs[sub][r];
        }
    }
}

__global__ __launch_bounds__(256) void edge_scatter(
    const float* __restrict__ x,
    const int*   __restrict__ ei,
    const float* __restrict__ ea,
    const float* __restrict__ w1,
    const float* __restrict__ b1,
    const float* __restrict__ w2,
    const float* __restrict__ b2,
    int*   __restrict__ cursor,
    float* __restrict__ msg)
{
    __shared__ hfrag8 s_B[KTILES * 64];        // 17408 B: B-frags fp16
    __shared__ float  s_hm[256 * 17];          // 17408 B: h (f16 [k][e]) then msg (f32 [e][o] stride 17)
    __shared__ float4 s_w1[IN_D * HID_D / 4];  // 2 KB
    __shared__ float4 s_b1[HID_D / 4];         // 128 B
    __shared__ int    s_src[256];              // 1 KB

    const int t = threadIdx.x;
    const int e = blockIdx.x * 256 + t;        // original edge order, grid exact

    const int src = clampn(ei[e]);
    const int dst = clampn(ei[N_EDGES + e]);
    const int slot = atomicAdd(&cursor[dst], 1);
    s_src[t] = src;

    stage_weights(w1, b1, w2, b2, s_w1, s_b1, s_B, t);
    __syncthreads();                           // staging + s_src visible

    edge_mlp_to_lds(ea, e, s_w1, s_b1, s_hm, t);
    __syncthreads();                           // h visible

    f32x4 accs[4];
    mfma_msgs(x, s_src, s_hm, s_B, t, accs);
    __syncthreads();                           // all s_h reads done
    write_cfrags(s_hm, accs, t);
    __syncthreads();                           // msg rows visible

    const float* p = &s_hm[t * 17];
    float4* mp = reinterpret_cast<float4*>(msg + (size_t)slot * 16);
    mp[0] = make_float4(p[0],  p[1],  p[2],  p[3]);
    mp[1] = make_float4(p[4],  p[5],  p[6],  p[7]);
    mp[2] = make_float4(p[8],  p[9],  p[10], p[11]);
    mp[3] = make_float4(p[12], p[13], p[14], p[15]);
}

// ---------------- gather + finalize ----------------

__global__ __launch_bounds__(256) void gather_finalize(
    const float* __restrict__ x,
    const float* __restrict__ root,
    const float* __restrict__ bias,
    const float* __restrict__ msg,
    const int*   __restrict__ cursor,   // post-edge: segment END
    const int*   __restrict__ deg,
    float* __restrict__ out)
{
    __shared__ float4 s_root[IN_D * OUT_D / 4];
    __shared__ float4 s_bias[OUT_D / 4];
    const int t = threadIdx.x;
    if (t < IN_D * OUT_D / 4) s_root[t] = reinterpret_cast<const float4*>(root)[t];
    if (t < OUT_D / 4)        s_bias[t] = reinterpret_cast<const float4*>(bias)[t];
    __syncthreads();

    const int n = blockIdx.x * 256 + t;
    if (n >= N_NODES) return;

    const int d   = deg[n];
    const int end = cursor[n];
    const int j0  = end - d;

    float4 a0 = make_float4(0.f,0.f,0.f,0.f), a1 = a0, a2 = a0, a3 = a0;
    for (int j = j0; j < end; ++j) {
        const float4* mp = reinterpret_cast<const float4*>(msg + (size_t)j * 16);
        a0 = add4(a0, mp[0]); a1 = add4(a1, mp[1]);
        a2 = add4(a2, mp[2]); a3 = add4(a3, mp[3]);
    }

    const float inv = 1.0f / (float)(d > 1 ? d : 1);
    float4 m0 = make_float4(a0.x*inv + s_bias[0].x, a0.y*inv + s_bias[0].y,
                            a0.z*inv + s_bias[0].z, a0.w*inv + s_bias[0].w);
    float4 m1 = make_float4(a1.x*inv + s_bias[1].x, a1.y*inv + s_bias[1].y,
                            a1.z*inv + s_bias[1].z, a1.w*inv + s_bias[1].w);
    float4 m2 = make_float4(a2.x*inv + s_bias[2].x, a2.y*inv + s_bias[2].y,
                            a2.z*inv + s_bias[2].z, a2.w*inv + s_bias[2].w);
    float4 m3 = make_float4(a3.x*inv + s_bias[3].x, a3.y*inv + s_bias[3].y,
                            a3.z*inv + s_bias[3].z, a3.w*inv + s_bias[3].w);

    float xs[IN_D];
    {
        const float4* xp = reinterpret_cast<const float4*>(x) + (size_t)n * 4;
        float4 b0 = xp[0], b1v = xp[1], b2v = xp[2], b3 = xp[3];
        xs[0]=b0.x;  xs[1]=b0.y;  xs[2]=b0.z;  xs[3]=b0.w;
        xs[4]=b1v.x; xs[5]=b1v.y; xs[6]=b1v.z; xs[7]=b1v.w;
        xs[8]=b2v.x; xs[9]=b2v.y; xs[10]=b2v.z; xs[11]=b2v.w;
        xs[12]=b3.x; xs[13]=b3.y; xs[14]=b3.z; xs[15]=b3.w;
    }
    #pragma unroll
    for (int i = 0; i < IN_D; ++i) {
        const float xi = xs[i];
        fma4(xi, s_root[i*4+0], m0);
        fma4(xi, s_root[i*4+1], m1);
        fma4(xi, s_root[i*4+2], m2);
        fma4(xi, s_root[i*4+3], m3);
    }

    float4* op = reinterpret_cast<float4*>(out) + (size_t)n * 4;
    op[0] = m0; op[1] = m1; op[2] = m2; op[3] = m3;
}

extern "C" void kernel_launch(void* const* d_in, const int* in_sizes, int n_in,
                              void* d_out, int out_size, void* d_ws, size_t ws_size,
                              hipStream_t stream) {
    const float* x    = (const float*)d_in[0];
    const int*   ei   = (const int*)  d_in[1];
    const float* ea   = (const float*)d_in[2];
    const float* w1   = (const float*)d_in[3];
    const float* b1   = (const float*)d_in[4];
    const float* w2   = (const float*)d_in[5];
    const float* b2   = (const float*)d_in[6];
    const float* root = (const float*)d_in[7];
    const float* bias = (const float*)d_in[8];
    float* out = (float*)d_out;

    // ws layout (~51.6 MB, within the R6-proven envelope)
    int* deg    = (int*)d_ws;                 // 50000
    int* gtot   = deg + N_NODES;              // 1
    int* cursor = gtot + 4;                   // 50000 (keep 16B alignment)
    float* msg  = (float*)(cursor + N_NODES + 12); // E*16 f32, 16B-aligned

    hipMemsetAsync(deg, 0, (N_NODES + 4) * sizeof(int), stream);  // deg + gtot
    deg_k          <<<NBLK_E, 256, 0, stream>>>(ei, deg);
    scan_fused     <<<NBLK_N, 256, 0, stream>>>(deg, cursor, gtot);
    edge_scatter   <<<NBLK_E, 256, 0, stream>>>(x, ei, ea, w1, b1, w2, b2, cursor, msg);
    gather_finalize<<<NBLK_N, 256, 0, stream>>>(x, root, bias, msg, cursor, deg, out);
}